// Round 9
// baseline (227.327 us; speedup 1.0000x reference)
//
#include <hip/hip_runtime.h>
#include <hip/hip_bf16.h>
#include <math.h>

#define D_MODEL 1024
#define NUM_HEADS 16
#define D_K 64
#define SEQ 1024
#define BATCH 2

typedef __hip_bfloat16 bf16;
typedef __bf16 bf16x8 __attribute__((ext_vector_type(8)));
typedef __bf16 bf16x4 __attribute__((ext_vector_type(4)));
typedef float floatx4 __attribute__((ext_vector_type(4)));

__device__ __forceinline__ floatx4 mfma16(bf16x8 a, bf16x8 b, floatx4 c) {
    return __builtin_amdgcn_mfma_f32_16x16x32_bf16(a, b, c, 0, 0, 0);
}

// ---------------------------------------------------------------------------
// Dtype probe: flag=1 -> fp32 inputs, 0 -> bf16 (verified in r2-r8).
// ---------------------------------------------------------------------------
__global__ void detect_dtype_kernel(const void* __restrict__ x, int* __restrict__ flag) {
    __shared__ int cnt[256];
    const float* xf = (const float*)x;
    const int tid = threadIdx.x;
    int sane = 0;
    for (int i = tid; i < 4096; i += 256) {
        float v = xf[i];
        float a = fabsf(v);
        if (v == 0.0f || (a > 1e-8f && a < 1e8f)) sane++;
    }
    cnt[tid] = sane;
    __syncthreads();
    for (int s = 128; s > 0; s >>= 1) {
        if (tid < s) cnt[tid] += cnt[tid + s];
        __syncthreads();
    }
    if (tid == 0) flag[0] = (cnt[0] > 3686) ? 1 : 0;
}

// ---------------------------------------------------------------------------
// Fused convert of all 10 inputs into the canonical bf16 region.
// ---------------------------------------------------------------------------
struct ConvSrcs { const void* p[10]; };

__global__ __launch_bounds__(256) void convert_all_kernel(ConvSrcs srcs,
                                                          bf16* __restrict__ dstbase,
                                                          const int* __restrict__ flag) {
    const long long e = ((long long)blockIdx.x * 256 + threadIdx.x) * 8;
    int seg; long long base;
    if      (e < 2097152LL) { seg = 0; base = 0; }
    else if (e < 3145728LL) { seg = 1; base = 2097152LL; }
    else if (e < 4194304LL) { seg = 2; base = 3145728LL; }
    else if (e < 5242880LL) { seg = 3; base = 4194304LL; }
    else if (e < 6291456LL) { seg = 4; base = 5242880LL; }
    else if (e < 6292480LL) { seg = 5; base = 6291456LL; }
    else if (e < 6293504LL) { seg = 6; base = 6292480LL; }
    else if (e < 6294528LL) { seg = 7; base = 6293504LL; }
    else if (e < 6295552LL) { seg = 8; base = 6294528LL; }
    else                    { seg = 9; base = 6295552LL; }
    const long long local = e - base;
    __bf16 tmp[8];
    if (*flag) {
        const float* s = (const float*)srcs.p[seg] + local;
#pragma unroll
        for (int t = 0; t < 8; ++t) tmp[t] = (__bf16)s[t];
        *(bf16x8*)(void*)(dstbase + e) = *(const bf16x8*)tmp;
    } else {
        *(bf16x8*)(void*)(dstbase + e) =
            *(const bf16x8*)(const void*)((const bf16*)srcs.p[seg] + local);
    }
}

// ---------------------------------------------------------------------------
// Fused QKV GEMM, 128x64 tiles (768 blocks -> 3/CU). wsel = blockIdx.x>>4.
// For wsel==2 (V), the epilogue transposes per-head through LDS and writes
// Vt[((b*16+h)*64+d)*SEQ + s] directly.
// ---------------------------------------------------------------------------
__global__ __launch_bounds__(256) void gemm_qkv_kernel(const bf16* __restrict__ x,
        const bf16* __restrict__ Wq, const bf16* __restrict__ Wk, const bf16* __restrict__ Wv,
        const bf16* __restrict__ bq, const bf16* __restrict__ bk, const bf16* __restrict__ bv,
        bf16* __restrict__ Qb, bf16* __restrict__ Kb, bf16* __restrict__ Vt) {
    const int wsel = blockIdx.x >> 4;
    const int n0 = (blockIdx.x & 15) * 64;
    const int m0 = blockIdx.y * 128;
    const bf16* W    = (wsel == 0) ? Wq : ((wsel == 1) ? Wk : Wv);
    const bf16* bias = (wsel == 0) ? bq : ((wsel == 1) ? bk : bv);

    __shared__ __bf16 As[128][72];
    __shared__ __bf16 Bs[64][72];
    const int tid = threadIdx.x;
    const int wave = tid >> 6, lane = tid & 63, quad = lane >> 4, l16 = lane & 15;
    const int wr = (wave >> 1) * 64, wc = (wave & 1) * 32;
    const int arow = tid >> 1, acg = (tid & 1) * 32;
    const int brow = tid >> 2, bcg = (tid & 3) * 16;

    floatx4 acc[4][2];
#pragma unroll
    for (int r = 0; r < 4; ++r)
#pragma unroll
        for (int c = 0; c < 2; ++c) acc[r][c] = (floatx4)0.f;

    for (int k0 = 0; k0 < 1024; k0 += 64) {
        const bf16* ag = x + (size_t)(m0 + arow) * 1024 + k0 + acg;
        const bf16* bg = W + (size_t)(n0 + brow) * 1024 + k0 + bcg;
        bf16x8 av[4], bv2[2];
#pragma unroll
        for (int c = 0; c < 4; ++c) av[c] = *(const bf16x8*)(const void*)(ag + c * 8);
#pragma unroll
        for (int c = 0; c < 2; ++c) bv2[c] = *(const bf16x8*)(const void*)(bg + c * 8);
        __syncthreads();
#pragma unroll
        for (int c = 0; c < 4; ++c) *(bf16x8*)&As[arow][acg + c * 8] = av[c];
#pragma unroll
        for (int c = 0; c < 2; ++c) *(bf16x8*)&Bs[brow][bcg + c * 8] = bv2[c];
        __syncthreads();
#pragma unroll
        for (int kk = 0; kk < 2; ++kk) {
            bf16x8 af[4], bfr[2];
#pragma unroll
            for (int r = 0; r < 4; ++r)
                af[r] = *(const bf16x8*)&As[wr + r * 16 + l16][kk * 32 + quad * 8];
#pragma unroll
            for (int c = 0; c < 2; ++c)
                bfr[c] = *(const bf16x8*)&Bs[wc + c * 16 + l16][kk * 32 + quad * 8];
#pragma unroll
            for (int r = 0; r < 4; ++r)
#pragma unroll
                for (int c = 0; c < 2; ++c)
                    acc[r][c] = mfma16(af[r], bfr[c], acc[r][c]);
        }
    }

    if (wsel < 2) {
        bf16* Cb = (wsel == 0) ? Qb : Kb;
#pragma unroll
        for (int c = 0; c < 2; ++c) {
            const int col = n0 + wc + c * 16 + l16;
            const float bvl = (float)bias[col];
#pragma unroll
            for (int r = 0; r < 4; ++r)
#pragma unroll
                for (int v = 0; v < 4; ++v) {
                    const int row = m0 + wr + r * 16 + quad * 4 + v;
                    Cb[(size_t)row * 1024 + col] = (bf16)(acc[r][c][v] + bvl);
                }
        }
    } else {
        __bf16* Ls = &As[0][0];
        __syncthreads();
#pragma unroll
        for (int c = 0; c < 2; ++c) {
            const int col = wc + c * 16 + l16;  // d
            const float bvl = (float)bias[n0 + col];
#pragma unroll
            for (int r = 0; r < 4; ++r)
#pragma unroll
                for (int v = 0; v < 4; ++v) {
                    const int row = wr + r * 16 + quad * 4 + v;  // s_local
                    Ls[col * 132 + row] = (__bf16)(acc[r][c][v] + bvl);
                }
        }
        __syncthreads();
        const int b = m0 >> 10, s0 = m0 & 1023, h = n0 >> 6;
        const int d = tid >> 2, sg = (tid & 3) * 32;
        bf16* g = Vt + ((size_t)((b * NUM_HEADS + h) * 64 + d)) * SEQ + s0 + sg;
#pragma unroll
        for (int c = 0; c < 32; c += 8)
            *(bf16x8*)(void*)(g + c) = *(const bf16x8*)&Ls[d * 132 + sg + c];
    }
}

// ---------------------------------------------------------------------------
// Flash attention, relative positions, NO-MAX softmax, BARRIER-FREE j-loop.
// Block = 128 q-rows x (h, b, jsel in [0,4)); 256 thr = 4 waves x 32 rows,
// grid 8*16*8 = 1024 = 4 blocks/CU (tail-free). All MFMA operands except the
// wave-private T'/P scratch come straight from global (L2-hot): K b-frags,
// V^T b-frags (Vt layout IS B-operand order), Er b-frags, Q a-frags. No
// __syncthreads in the loop -> 16 independent wave chains per CU instead of
// 4 convoyed blocks (r8: 2 barriers/tile, all pipes <30% busy).
// l accumulated via static ones-region MFMA (init once + 1 barrier).
// ---------------------------------------------------------------------------
__global__ __launch_bounds__(256, 4) void attn_mfma_kernel(const bf16* __restrict__ Q,
                                                           const bf16* __restrict__ Kc,
                                                           const bf16* __restrict__ Vt,
                                                           const bf16* __restrict__ Er,
                                                           bf16* __restrict__ Opart,
                                                           float* __restrict__ Ml) {
    const int i0 = blockIdx.x * 128;
    const int h = blockIdx.y;
    const int b = blockIdx.z >> 2, jsel = blockIdx.z & 3;
    const int tid = threadIdx.x;
    const int wave = tid >> 6, lane = tid & 63, quad = lane >> 4, l16 = lane & 15;

    __shared__ __bf16 scr_all[4][3264];  // per-wave: T' [96][34] / P [32][72]
    __shared__ __bf16 ones[16][72];      // row 0 = 1.0, rows 1..15 = 0
    __bf16* scr = &scr_all[wave][0];

    for (int e = tid; e < 16 * 72; e += 256)
        (&ones[0][0])[e] = (e < 72) ? (__bf16)1.0f : (__bf16)0.0f;
    __syncthreads();  // only barrier: ones visible before first PV

    // Q a-frags direct from global (one-time)
    bf16x8 aq[2][2];
#pragma unroll
    for (int half = 0; half < 2; ++half)
#pragma unroll
        for (int kk = 0; kk < 2; ++kk) {
            const bf16* qp = Q +
                ((size_t)(b * SEQ + i0 + wave * 32 + half * 16 + l16)) * D_MODEL +
                h * 64 + kk * 32 + quad * 8;
            aq[half][kk] = *(const bf16x8*)(const void*)qp;
        }

    floatx4 oacc[5][2];   // ct 0..3: O columns; ct 4: row-sum l
#pragma unroll
    for (int ct = 0; ct < 5; ++ct)
#pragma unroll
        for (int half = 0; half < 2; ++half) oacc[ct][half] = (floatx4)0.f;

    const int eb = 960 + i0;
    const bf16* Kg = Kc + (size_t)b * SEQ * D_MODEL + h * 64;
    const bf16* Vtg = Vt + (size_t)((b * NUM_HEADS + h) * 64) * SEQ;
    const int jbeg = jsel * 256;

    for (int t = 0; t < 4; ++t) {
        const int j0 = jbeg + t * 64;

        // BD: Er b-frags from global, MFMA, spill transposed to wave scratch
#pragma unroll
        for (int ct = 0; ct < 6; ++ct) {
            const int erow = eb - j0 + wave * 32 + ct * 16 + l16;
            const bf16* ep = Er + (size_t)erow * 64 + quad * 8;
            bf16x8 be0 = *(const bf16x8*)(const void*)ep;
            bf16x8 be1 = *(const bf16x8*)(const void*)(ep + 32);
#pragma unroll
            for (int half = 0; half < 2; ++half) {
                floatx4 tv = (floatx4)0.f;
                tv = mfma16(aq[half][0], be0, tv);
                tv = mfma16(aq[half][1], be1, tv);
                bf16x4 tb;
#pragma unroll
                for (int v = 0; v < 4; ++v) tb[v] = (__bf16)tv[v];
                *(bf16x4*)(void*)(scr + (ct * 16 + l16) * 34 + half * 16 + quad * 4) = tb;
            }
        }
        // AC = Q.K^T, K b-frags direct from global
        floatx4 sfrag[4][2];
#pragma unroll
        for (int ct = 0; ct < 4; ++ct) {
            const bf16* kp = Kg + (size_t)(j0 + ct * 16 + l16) * D_MODEL + quad * 8;
            bf16x8 bk0 = *(const bf16x8*)(const void*)kp;
            bf16x8 bk1 = *(const bf16x8*)(const void*)(kp + 32);
#pragma unroll
            for (int half = 0; half < 2; ++half) {
                floatx4 s = (floatx4)0.f;
                s = mfma16(aq[half][0], bk0, s);
                s = mfma16(aq[half][1], bk1, s);
                sfrag[ct][half] = s;
            }
        }
        // Phase 1: gather ALL BD values (every T' read completes into sfrag)
#pragma unroll
        for (int ct = 0; ct < 4; ++ct)
#pragma unroll
            for (int half = 0; half < 2; ++half)
#pragma unroll
                for (int v = 0; v < 4; ++v) {
                    const int rl = half * 16 + quad * 4 + v;
                    const int cl = 63 + rl - (ct * 16 + l16);
                    sfrag[ct][half][v] =
                        (sfrag[ct][half][v] + (float)scr[cl * 34 + rl]) * 0.125f;
                }
        // Phase 2: P = exp(score) -> scratch (T' dead; no RAW hazard)
#pragma unroll
        for (int ct = 0; ct < 4; ++ct)
#pragma unroll
            for (int half = 0; half < 2; ++half)
#pragma unroll
                for (int v = 0; v < 4; ++v) {
                    const int rl = half * 16 + quad * 4 + v;
                    scr[rl * 72 + ct * 16 + l16] = (__bf16)__expf(sfrag[ct][half][v]);
                }
        // O += P.V (V^T b-frags direct from global) ; l += P.1 (ones LDS)
        bf16x8 ap[2][2];
#pragma unroll
        for (int half = 0; half < 2; ++half)
#pragma unroll
            for (int kk = 0; kk < 2; ++kk)
                ap[half][kk] = *(const bf16x8*)(const void*)(
                    scr + (half * 16 + l16) * 72 + kk * 32 + quad * 8);
#pragma unroll
        for (int ct = 0; ct < 4; ++ct) {
            const bf16* vp = Vtg + (size_t)(ct * 16 + l16) * SEQ + j0 + quad * 8;
            bf16x8 bv0 = *(const bf16x8*)(const void*)vp;
            bf16x8 bv1 = *(const bf16x8*)(const void*)(vp + 32);
#pragma unroll
            for (int half = 0; half < 2; ++half) {
                oacc[ct][half] = mfma16(ap[half][0], bv0, oacc[ct][half]);
                oacc[ct][half] = mfma16(ap[half][1], bv1, oacc[ct][half]);
            }
        }
        {
            bf16x8 bo0 = *(const bf16x8*)&ones[l16][quad * 8];
            bf16x8 bo1 = *(const bf16x8*)&ones[l16][32 + quad * 8];
#pragma unroll
            for (int half = 0; half < 2; ++half) {
                oacc[4][half] = mfma16(ap[half][0], bo0, oacc[4][half]);
                oacc[4][half] = mfma16(ap[half][1], bo1, oacc[4][half]);
            }
        }
    }

    // epilogue: unnormalized bf16 O-partials + l
    bf16* Op = Opart + (size_t)jsel * 2097152;
#pragma unroll
    for (int ct = 0; ct < 4; ++ct)
#pragma unroll
        for (int half = 0; half < 2; ++half)
#pragma unroll
            for (int v = 0; v < 4; ++v) {
                const int row = i0 + wave * 32 + half * 16 + quad * 4 + v;
                const int col = h * 64 + ct * 16 + l16;
                Op[((size_t)(b * SEQ + row)) * D_MODEL + col] = (bf16)oacc[ct][half][v];
            }
    if (l16 == 0) {
        const int base = ((jsel * 2 + b) * 16 + h) * 1024;
#pragma unroll
        for (int half = 0; half < 2; ++half)
#pragma unroll
            for (int v = 0; v < 4; ++v) {
                const int ig = i0 + wave * 32 + half * 16 + quad * 4 + v;
                Ml[base + ig] = oacc[4][half][v];
            }
    }
}

// ---------------------------------------------------------------------------
// Combine 4 j-split partials: Ob = (sum O~_s) / (sum l_s).
// ---------------------------------------------------------------------------
__global__ __launch_bounds__(256) void combine_kernel(const bf16* __restrict__ Opart,
                                                      const float* __restrict__ Ml,
                                                      bf16* __restrict__ Ob) {
    const int e = (blockIdx.x * 256 + threadIdx.x) * 4;
    const int row = e >> 10, col = e & 1023;
    const int b = row >> 10, i = row & 1023, h = col >> 6;
    float l = 0.f;
#pragma unroll
    for (int s = 0; s < 4; ++s) l += Ml[(((s * 2 + b) * 16 + h) << 10) + i];
    const float inv = 1.0f / l;
    float o[4] = {0.f, 0.f, 0.f, 0.f};
#pragma unroll
    for (int s = 0; s < 4; ++s) {
        bf16x4 ov = *(const bf16x4*)(const void*)(Opart + (size_t)s * 2097152 + e);
#pragma unroll
        for (int v = 0; v < 4; ++v) o[v] += (float)ov[v];
    }
    bf16x4 r;
#pragma unroll
    for (int v = 0; v < 4; ++v) r[v] = (__bf16)(o[v] * inv);
    *(bf16x4*)(void*)(Ob + e) = r;
}

// ---------------------------------------------------------------------------
// Output GEMM: out[m,n] = bo[n] + sum_k Ob[m,k]*Wo[n,k]. 64x64 tiles
// (512 blocks -> 2/CU), dual-dtype store.
// ---------------------------------------------------------------------------
__global__ __launch_bounds__(256) void gemm_out_kernel(const bf16* __restrict__ A,
        const bf16* __restrict__ W, const bf16* __restrict__ bias,
        void* __restrict__ C, const int* __restrict__ flag) {
    const int n0 = blockIdx.x * 64;
    const int m0 = blockIdx.y * 64;
    __shared__ __bf16 As[64][72];
    __shared__ __bf16 Bs[64][72];
    const int tid = threadIdx.x;
    const int wave = tid >> 6, lane = tid & 63, quad = lane >> 4, l16 = lane & 15;
    const int wr = (wave >> 1) * 32, wc = (wave & 1) * 32;
    const int srow = tid >> 2, scg = (tid & 3) * 16;

    floatx4 acc[2][2];
#pragma unroll
    for (int r = 0; r < 2; ++r)
#pragma unroll
        for (int c = 0; c < 2; ++c) acc[r][c] = (floatx4)0.f;

    for (int k0 = 0; k0 < 1024; k0 += 64) {
        const bf16* ag = A + (size_t)(m0 + srow) * 1024 + k0 + scg;
        const bf16* bg = W + (size_t)(n0 + srow) * 1024 + k0 + scg;
        bf16x8 av0 = *(const bf16x8*)(const void*)ag;
        bf16x8 av1 = *(const bf16x8*)(const void*)(ag + 8);
        bf16x8 bv0 = *(const bf16x8*)(const void*)bg;
        bf16x8 bv1 = *(const bf16x8*)(const void*)(bg + 8);
        __syncthreads();
        *(bf16x8*)&As[srow][scg]     = av0;
        *(bf16x8*)&As[srow][scg + 8] = av1;
        *(bf16x8*)&Bs[srow][scg]     = bv0;
        *(bf16x8*)&Bs[srow][scg + 8] = bv1;
        __syncthreads();
#pragma unroll
        for (int kk = 0; kk < 2; ++kk) {
            bf16x8 af[2], bfr[2];
#pragma unroll
            for (int r = 0; r < 2; ++r)
                af[r] = *(const bf16x8*)&As[wr + r * 16 + l16][kk * 32 + quad * 8];
#pragma unroll
            for (int c = 0; c < 2; ++c)
                bfr[c] = *(const bf16x8*)&Bs[wc + c * 16 + l16][kk * 32 + quad * 8];
#pragma unroll
            for (int r = 0; r < 2; ++r)
#pragma unroll
                for (int c = 0; c < 2; ++c)
                    acc[r][c] = mfma16(af[r], bfr[c], acc[r][c]);
        }
    }
#pragma unroll
    for (int c = 0; c < 2; ++c) {
        const int col = n0 + wc + c * 16 + l16;
        const float bvl = (float)bias[col];
#pragma unroll
        for (int r = 0; r < 2; ++r)
#pragma unroll
            for (int v = 0; v < 4; ++v) {
                const int row = m0 + wr + r * 16 + quad * 4 + v;
                const float val = acc[r][c][v] + bvl;
                const size_t idx = (size_t)row * 1024 + col;
                if (*flag) ((float*)C)[idx] = val;
                else       ((bf16*)C)[idx] = (bf16)val;
            }
    }
}

// ---------------------------------------------------------------------------
extern "C" void kernel_launch(void* const* d_in, const int* in_sizes, int n_in,
                              void* d_out, int out_size, void* d_ws, size_t ws_size,
                              hipStream_t stream) {
    const size_t E_X = 2097152;       // 2048 x 1024
    const size_t E_CANON = 6426624;

    char* ws = (char*)d_ws;
    int* flag = (int*)ws;
    bf16* canon = (bf16*)(ws + 16);
    bf16* xc  = canon;
    bf16* Wqc = canon + 2097152;
    bf16* Wkc = canon + 3145728;
    bf16* Wvc = canon + 4194304;
    bf16* Woc = canon + 5242880;
    bf16* bqc = canon + 6291456;
    bf16* bkc = canon + 6292480;
    bf16* bvc = canon + 6293504;
    bf16* boc = canon + 6294528;
    bf16* Erc = canon + 6295552;
    bf16* p = canon + E_CANON;
    bf16* Qb    = p;  p += E_X;       // reused as Ob after combine
    bf16* Kb    = p;  p += E_X;
    bf16* Vt    = p;  p += E_X;
    bf16* Opart = p;  p += 4 * E_X;   // bf16 unnormalized partials, 4 j-splits
    float* Ml   = (float*)p;          // [4 jsel][2 b][16 h][1024 i] = 131072 f32

    detect_dtype_kernel<<<1, 256, 0, stream>>>(d_in[0], flag);

    ConvSrcs cs;
    cs.p[0] = d_in[0]; cs.p[1] = d_in[1]; cs.p[2] = d_in[3]; cs.p[3] = d_in[5];
    cs.p[4] = d_in[7]; cs.p[5] = d_in[2]; cs.p[6] = d_in[4]; cs.p[7] = d_in[6];
    cs.p[8] = d_in[8]; cs.p[9] = d_in[9];
    convert_all_kernel<<<3138, 256, 0, stream>>>(cs, canon, flag);

    gemm_qkv_kernel<<<dim3(48, 16), 256, 0, stream>>>(xc, Wqc, Wkc, Wvc,
                                                      bqc, bkc, bvc, Qb, Kb, Vt);

    attn_mfma_kernel<<<dim3(8, 16, 8), 256, 0, stream>>>(Qb, Kb, Vt, Erc, Opart, Ml);

    combine_kernel<<<2048, 256, 0, stream>>>(Opart, Ml, Qb);  // Ob overlays Qb

    gemm_out_kernel<<<dim3(16, 32), 256, 0, stream>>>(Qb, Woc, boc, d_out, flag);
}

// Round 10
// 186.726 us; speedup vs baseline: 1.2174x; 1.2174x over previous
//
#include <hip/hip_runtime.h>
#include <hip/hip_bf16.h>
#include <math.h>

#define D_MODEL 1024
#define NUM_HEADS 16
#define D_K 64
#define SEQ 1024
#define BATCH 2

typedef __hip_bfloat16 bf16;
typedef __bf16 bf16x8 __attribute__((ext_vector_type(8)));
typedef __bf16 bf16x4 __attribute__((ext_vector_type(4)));
typedef float floatx4 __attribute__((ext_vector_type(4)));

__device__ __forceinline__ floatx4 mfma16(bf16x8 a, bf16x8 b, floatx4 c) {
    return __builtin_amdgcn_mfma_f32_16x16x32_bf16(a, b, c, 0, 0, 0);
}

// ---------------------------------------------------------------------------
// Dtype probe: flag=1 -> fp32 inputs, 0 -> bf16 (verified in r2-r9).
// ---------------------------------------------------------------------------
__global__ void detect_dtype_kernel(const void* __restrict__ x, int* __restrict__ flag) {
    __shared__ int cnt[256];
    const float* xf = (const float*)x;
    const int tid = threadIdx.x;
    int sane = 0;
    for (int i = tid; i < 4096; i += 256) {
        float v = xf[i];
        float a = fabsf(v);
        if (v == 0.0f || (a > 1e-8f && a < 1e8f)) sane++;
    }
    cnt[tid] = sane;
    __syncthreads();
    for (int s = 128; s > 0; s >>= 1) {
        if (tid < s) cnt[tid] += cnt[tid + s];
        __syncthreads();
    }
    if (tid == 0) flag[0] = (cnt[0] > 3686) ? 1 : 0;
}

// ---------------------------------------------------------------------------
// Fused convert of all 10 inputs into the canonical bf16 region.
// ---------------------------------------------------------------------------
struct ConvSrcs { const void* p[10]; };

__global__ __launch_bounds__(256) void convert_all_kernel(ConvSrcs srcs,
                                                          bf16* __restrict__ dstbase,
                                                          const int* __restrict__ flag) {
    const long long e = ((long long)blockIdx.x * 256 + threadIdx.x) * 8;
    int seg; long long base;
    if      (e < 2097152LL) { seg = 0; base = 0; }
    else if (e < 3145728LL) { seg = 1; base = 2097152LL; }
    else if (e < 4194304LL) { seg = 2; base = 3145728LL; }
    else if (e < 5242880LL) { seg = 3; base = 4194304LL; }
    else if (e < 6291456LL) { seg = 4; base = 5242880LL; }
    else if (e < 6292480LL) { seg = 5; base = 6291456LL; }
    else if (e < 6293504LL) { seg = 6; base = 6292480LL; }
    else if (e < 6294528LL) { seg = 7; base = 6293504LL; }
    else if (e < 6295552LL) { seg = 8; base = 6294528LL; }
    else                    { seg = 9; base = 6295552LL; }
    const long long local = e - base;
    __bf16 tmp[8];
    if (*flag) {
        const float* s = (const float*)srcs.p[seg] + local;
#pragma unroll
        for (int t = 0; t < 8; ++t) tmp[t] = (__bf16)s[t];
        *(bf16x8*)(void*)(dstbase + e) = *(const bf16x8*)tmp;
    } else {
        *(bf16x8*)(void*)(dstbase + e) =
            *(const bf16x8*)(const void*)((const bf16*)srcs.p[seg] + local);
    }
}

// ---------------------------------------------------------------------------
// Fused QKV GEMM, 128x64 tiles (768 blocks -> 3/CU), SOFTWARE-PIPELINED:
// next k-tile is loaded into registers AFTER the LDS write barrier, so the
// ~400-cyc global latency overlaps the 16-MFMA compute phase (r8 exposed it
// serially inside the loop). wsel = blockIdx.x>>4; wsel==2 (V) epilogue
// transposes per-head through LDS and writes Vt directly.
// ---------------------------------------------------------------------------
__global__ __launch_bounds__(256) void gemm_qkv_kernel(const bf16* __restrict__ x,
        const bf16* __restrict__ Wq, const bf16* __restrict__ Wk, const bf16* __restrict__ Wv,
        const bf16* __restrict__ bq, const bf16* __restrict__ bk, const bf16* __restrict__ bv,
        bf16* __restrict__ Qb, bf16* __restrict__ Kb, bf16* __restrict__ Vt) {
    const int wsel = blockIdx.x >> 4;
    const int n0 = (blockIdx.x & 15) * 64;
    const int m0 = blockIdx.y * 128;
    const bf16* W    = (wsel == 0) ? Wq : ((wsel == 1) ? Wk : Wv);
    const bf16* bias = (wsel == 0) ? bq : ((wsel == 1) ? bk : bv);

    __shared__ __bf16 As[128][72];
    __shared__ __bf16 Bs[64][72];
    const int tid = threadIdx.x;
    const int wave = tid >> 6, lane = tid & 63, quad = lane >> 4, l16 = lane & 15;
    const int wr = (wave >> 1) * 64, wc = (wave & 1) * 32;
    const int arow = tid >> 1, acg = (tid & 1) * 32;
    const int brow = tid >> 2, bcg = (tid & 3) * 16;

    floatx4 acc[4][2];
#pragma unroll
    for (int r = 0; r < 4; ++r)
#pragma unroll
        for (int c = 0; c < 2; ++c) acc[r][c] = (floatx4)0.f;

    const bf16* agb = x + (size_t)(m0 + arow) * 1024 + acg;
    const bf16* bgb = W + (size_t)(n0 + brow) * 1024 + bcg;

    bf16x8 av[4], bv2[2];
#pragma unroll
    for (int c = 0; c < 4; ++c) av[c] = *(const bf16x8*)(const void*)(agb + c * 8);
#pragma unroll
    for (int c = 0; c < 2; ++c) bv2[c] = *(const bf16x8*)(const void*)(bgb + c * 8);

    for (int k0 = 0; k0 < 1024; k0 += 64) {
        __syncthreads();   // prior-iter MFMA LDS reads done
#pragma unroll
        for (int c = 0; c < 4; ++c) *(bf16x8*)&As[arow][acg + c * 8] = av[c];
#pragma unroll
        for (int c = 0; c < 2; ++c) *(bf16x8*)&Bs[brow][bcg + c * 8] = bv2[c];
        __syncthreads();   // tile visible
        if (k0 < 960) {    // prefetch next tile (overlaps MFMA below)
            const bf16* ag = agb + k0 + 64;
            const bf16* bg = bgb + k0 + 64;
#pragma unroll
            for (int c = 0; c < 4; ++c) av[c] = *(const bf16x8*)(const void*)(ag + c * 8);
#pragma unroll
            for (int c = 0; c < 2; ++c) bv2[c] = *(const bf16x8*)(const void*)(bg + c * 8);
        }
#pragma unroll
        for (int kk = 0; kk < 2; ++kk) {
            bf16x8 af[4], bfr[2];
#pragma unroll
            for (int r = 0; r < 4; ++r)
                af[r] = *(const bf16x8*)&As[wr + r * 16 + l16][kk * 32 + quad * 8];
#pragma unroll
            for (int c = 0; c < 2; ++c)
                bfr[c] = *(const bf16x8*)&Bs[wc + c * 16 + l16][kk * 32 + quad * 8];
#pragma unroll
            for (int r = 0; r < 4; ++r)
#pragma unroll
                for (int c = 0; c < 2; ++c)
                    acc[r][c] = mfma16(af[r], bfr[c], acc[r][c]);
        }
    }

    if (wsel < 2) {
        bf16* Cb = (wsel == 0) ? Qb : Kb;
#pragma unroll
        for (int c = 0; c < 2; ++c) {
            const int col = n0 + wc + c * 16 + l16;
            const float bvl = (float)bias[col];
#pragma unroll
            for (int r = 0; r < 4; ++r)
#pragma unroll
                for (int v = 0; v < 4; ++v) {
                    const int row = m0 + wr + r * 16 + quad * 4 + v;
                    Cb[(size_t)row * 1024 + col] = (bf16)(acc[r][c][v] + bvl);
                }
        }
    } else {
        __bf16* Ls = &As[0][0];
        __syncthreads();
#pragma unroll
        for (int c = 0; c < 2; ++c) {
            const int col = wc + c * 16 + l16;  // d
            const float bvl = (float)bias[n0 + col];
#pragma unroll
            for (int r = 0; r < 4; ++r)
#pragma unroll
                for (int v = 0; v < 4; ++v) {
                    const int row = wr + r * 16 + quad * 4 + v;  // s_local
                    Ls[col * 132 + row] = (__bf16)(acc[r][c][v] + bvl);
                }
        }
        __syncthreads();
        const int b = m0 >> 10, s0 = m0 & 1023, h = n0 >> 6;
        const int d = tid >> 2, sg = (tid & 3) * 32;
        bf16* g = Vt + ((size_t)((b * NUM_HEADS + h) * 64 + d)) * SEQ + s0 + sg;
#pragma unroll
        for (int c = 0; c < 32; c += 8)
            *(bf16x8*)(void*)(g + c) = *(const bf16x8*)&Ls[d * 132 + sg + c];
    }
}

// ---------------------------------------------------------------------------
// Flash attention (r8 structure — best measured: 52.9 us, 26.5% occ).
// NO-MAX softmax; block = 128 q-rows x (h, b, jsel in [0,3)); 4 waves x 32
// rows; UNEVEN j-split (6/5/5 tiles of 64) -> 768 blocks = exactly 3/CU,
// tail-free. LDS-staged K/V^T (r9 showed global-direct b-frags lose 1.7x).
// K/V register prefetch; Er b-frags from global; l via ones-row MFMA.
// ---------------------------------------------------------------------------
__global__ __launch_bounds__(256, 3) void attn_mfma_kernel(const bf16* __restrict__ Q,
                                                           const bf16* __restrict__ Kc,
                                                           const bf16* __restrict__ Vt,
                                                           const bf16* __restrict__ Er,
                                                           bf16* __restrict__ Opart,
                                                           float* __restrict__ Ml) {
    const int i0 = blockIdx.x * 128;
    const int h = blockIdx.y;
    const int zz = blockIdx.z;
    const int b = zz / 3, jsel = zz - b * 3;
    const int tid = threadIdx.x;
    const int wave = tid >> 6, lane = tid & 63, quad = lane >> 4, l16 = lane & 15;

    const int jbeg = (jsel == 0) ? 0 : ((jsel == 1) ? 384 : 704);
    const int nt   = (jsel == 0) ? 6 : 5;

    __shared__ __bf16 Ks[64][72];
    __shared__ __bf16 Vs[80][72];        // rows 0..63: V^T tile; row 64: ones; 65..79: 0
    __shared__ __bf16 scr_all[4][3264];  // per-wave: T' [96][34] / P [32][72]; Qs alias
    __bf16* scr = &scr_all[wave][0];
    __bf16* Qs = &scr_all[0][0];

    for (int e = tid; e < 16 * 72; e += 256) {
        const int r = e / 72, c = e - r * 72;
        Vs[64 + r][c] = (r == 0) ? (__bf16)1.0f : (__bf16)0.0f;
    }
    {   // stage Q (128 rows x 64) into scr alias
        const int r = tid >> 1, cg = (tid & 1) * 32;
        const bf16* g = Q + ((size_t)(b * SEQ + i0 + r)) * D_MODEL + h * 64 + cg;
#pragma unroll
        for (int c = 0; c < 32; c += 8)
            *(bf16x8*)(void*)(Qs + r * 72 + cg + c) = *(const bf16x8*)(const void*)(g + c);
    }
    __syncthreads();
    bf16x8 aq[2][2];
#pragma unroll
    for (int half = 0; half < 2; ++half)
#pragma unroll
        for (int kk = 0; kk < 2; ++kk)
            aq[half][kk] = *(const bf16x8*)(const void*)(
                Qs + (wave * 32 + half * 16 + l16) * 72 + kk * 32 + quad * 8);

    floatx4 oacc[5][2];   // ct 0..3: O columns; ct 4: row-sum l
#pragma unroll
    for (int ct = 0; ct < 5; ++ct)
#pragma unroll
        for (int half = 0; half < 2; ++half) oacc[ct][half] = (floatx4)0.f;

    const int eb = 960 + i0;
    const bf16* Kg = Kc + (size_t)b * SEQ * D_MODEL + h * 64;
    const bf16* Vtg = Vt + (size_t)((b * NUM_HEADS + h) * 64) * SEQ;

    const int r4 = tid >> 2, c4 = (tid & 3) * 16;
    bf16x8 kp0, kp1, vp0, vp1;
    {   // prefetch first K/V tile
        const bf16* kg = Kg + (size_t)(jbeg + r4) * D_MODEL + c4;
        const bf16* vg = Vtg + (size_t)r4 * SEQ + jbeg + c4;
        kp0 = *(const bf16x8*)(const void*)kg;
        kp1 = *(const bf16x8*)(const void*)(kg + 8);
        vp0 = *(const bf16x8*)(const void*)vg;
        vp1 = *(const bf16x8*)(const void*)(vg + 8);
    }

    for (int t = 0; t < nt; ++t) {
        const int j0 = jbeg + t * 64;
        __syncthreads();  // barrier A: prior tile's Ks/Vs reads done
        *(bf16x8*)&Ks[r4][c4]     = kp0;
        *(bf16x8*)&Ks[r4][c4 + 8] = kp1;
        *(bf16x8*)&Vs[r4][c4]     = vp0;
        *(bf16x8*)&Vs[r4][c4 + 8] = vp1;
        __syncthreads();  // barrier B: tile visible
        if (t < nt - 1) { // prefetch next tile (overlaps compute below)
            const int jn = j0 + 64;
            const bf16* kg = Kg + (size_t)(jn + r4) * D_MODEL + c4;
            const bf16* vg = Vtg + (size_t)r4 * SEQ + jn + c4;
            kp0 = *(const bf16x8*)(const void*)kg;
            kp1 = *(const bf16x8*)(const void*)(kg + 8);
            vp0 = *(const bf16x8*)(const void*)vg;
            vp1 = *(const bf16x8*)(const void*)(vg + 8);
        }

        // BD: Er b-frags from global, MFMA, spill transposed to wave scratch
#pragma unroll
        for (int ct = 0; ct < 6; ++ct) {
            const int erow = eb - j0 + wave * 32 + ct * 16 + l16;
            const bf16* ep = Er + (size_t)erow * 64 + quad * 8;
            bf16x8 be0 = *(const bf16x8*)(const void*)ep;
            bf16x8 be1 = *(const bf16x8*)(const void*)(ep + 32);
#pragma unroll
            for (int half = 0; half < 2; ++half) {
                floatx4 tv = (floatx4)0.f;
                tv = mfma16(aq[half][0], be0, tv);
                tv = mfma16(aq[half][1], be1, tv);
                bf16x4 tb;
#pragma unroll
                for (int v = 0; v < 4; ++v) tb[v] = (__bf16)tv[v];
                *(bf16x4*)(void*)(scr + (ct * 16 + l16) * 34 + half * 16 + quad * 4) = tb;
            }
        }
        // AC = Q.K^T (hides T'-spill latency)
        floatx4 sfrag[4][2];
#pragma unroll
        for (int ct = 0; ct < 4; ++ct) {
            bf16x8 bk0 = *(const bf16x8*)&Ks[ct * 16 + l16][quad * 8];
            bf16x8 bk1 = *(const bf16x8*)&Ks[ct * 16 + l16][32 + quad * 8];
#pragma unroll
            for (int half = 0; half < 2; ++half) {
                floatx4 s = (floatx4)0.f;
                s = mfma16(aq[half][0], bk0, s);
                s = mfma16(aq[half][1], bk1, s);
                sfrag[ct][half] = s;
            }
        }
        // Phase 1: gather ALL BD values (every T' read completes into sfrag)
#pragma unroll
        for (int ct = 0; ct < 4; ++ct)
#pragma unroll
            for (int half = 0; half < 2; ++half)
#pragma unroll
                for (int v = 0; v < 4; ++v) {
                    const int rl = half * 16 + quad * 4 + v;
                    const int cl = 63 + rl - (ct * 16 + l16);
                    sfrag[ct][half][v] =
                        (sfrag[ct][half][v] + (float)scr[cl * 34 + rl]) * 0.125f;
                }
        // Phase 2: P = exp(score) -> scratch (T' dead; no RAW hazard)
#pragma unroll
        for (int ct = 0; ct < 4; ++ct)
#pragma unroll
            for (int half = 0; half < 2; ++half)
#pragma unroll
                for (int v = 0; v < 4; ++v) {
                    const int rl = half * 16 + quad * 4 + v;
                    scr[rl * 72 + ct * 16 + l16] = (__bf16)__expf(sfrag[ct][half][v]);
                }
        // O += P.V ; l += P.1
        bf16x8 ap[2][2];
#pragma unroll
        for (int half = 0; half < 2; ++half)
#pragma unroll
            for (int kk = 0; kk < 2; ++kk)
                ap[half][kk] = *(const bf16x8*)(const void*)(
                    scr + (half * 16 + l16) * 72 + kk * 32 + quad * 8);
#pragma unroll
        for (int ct = 0; ct < 5; ++ct) {
            bf16x8 bv0 = *(const bf16x8*)&Vs[ct * 16 + l16][quad * 8];
            bf16x8 bv1 = *(const bf16x8*)&Vs[ct * 16 + l16][32 + quad * 8];
#pragma unroll
            for (int half = 0; half < 2; ++half) {
                oacc[ct][half] = mfma16(ap[half][0], bv0, oacc[ct][half]);
                oacc[ct][half] = mfma16(ap[half][1], bv1, oacc[ct][half]);
            }
        }
    }

    // epilogue: unnormalized bf16 O-partials + l
    bf16* Op = Opart + (size_t)jsel * 2097152;
#pragma unroll
    for (int ct = 0; ct < 4; ++ct)
#pragma unroll
        for (int half = 0; half < 2; ++half)
#pragma unroll
            for (int v = 0; v < 4; ++v) {
                const int row = i0 + wave * 32 + half * 16 + quad * 4 + v;
                const int col = h * 64 + ct * 16 + l16;
                Op[((size_t)(b * SEQ + row)) * D_MODEL + col] = (bf16)oacc[ct][half][v];
            }
    if (l16 == 0) {
        const int base = ((jsel * 2 + b) * 16 + h) * 1024;
#pragma unroll
        for (int half = 0; half < 2; ++half)
#pragma unroll
            for (int v = 0; v < 4; ++v) {
                const int ig = i0 + wave * 32 + half * 16 + quad * 4 + v;
                Ml[base + ig] = oacc[4][half][v];
            }
    }
}

// ---------------------------------------------------------------------------
// Combine 3 j-split partials: Ob = (O1~+O2~+O3~) / (l1+l2+l3).
// ---------------------------------------------------------------------------
__global__ __launch_bounds__(256) void combine_kernel(const bf16* __restrict__ Opart,
                                                      const float* __restrict__ Ml,
                                                      bf16* __restrict__ Ob) {
    const int e = (blockIdx.x * 256 + threadIdx.x) * 4;
    const int row = e >> 10, col = e & 1023;
    const int b = row >> 10, i = row & 1023, h = col >> 6;
    float l = 0.f;
#pragma unroll
    for (int s = 0; s < 3; ++s) l += Ml[(((s * 2 + b) * 16 + h) << 10) + i];
    const float inv = 1.0f / l;
    bf16x4 o1 = *(const bf16x4*)(const void*)(Opart + e);
    bf16x4 o2 = *(const bf16x4*)(const void*)(Opart + 2097152 + e);
    bf16x4 o3 = *(const bf16x4*)(const void*)(Opart + 4194304 + e);
    bf16x4 o;
#pragma unroll
    for (int v = 0; v < 4; ++v)
        o[v] = (__bf16)(((float)o1[v] + (float)o2[v] + (float)o3[v]) * inv);
    *(bf16x4*)(void*)(Ob + e) = o;
}

// ---------------------------------------------------------------------------
// Output GEMM: out[m,n] = bo[n] + sum_k Ob[m,k]*Wo[n,k]. 64x64 tiles
// (512 blocks -> 2/CU), SOFTWARE-PIPELINED like qkv, dual-dtype store.
// ---------------------------------------------------------------------------
__global__ __launch_bounds__(256) void gemm_out_kernel(const bf16* __restrict__ A,
        const bf16* __restrict__ W, const bf16* __restrict__ bias,
        void* __restrict__ C, const int* __restrict__ flag) {
    const int n0 = blockIdx.x * 64;
    const int m0 = blockIdx.y * 64;
    __shared__ __bf16 As[64][72];
    __shared__ __bf16 Bs[64][72];
    const int tid = threadIdx.x;
    const int wave = tid >> 6, lane = tid & 63, quad = lane >> 4, l16 = lane & 15;
    const int wr = (wave >> 1) * 32, wc = (wave & 1) * 32;
    const int srow = tid >> 2, scg = (tid & 3) * 16;

    floatx4 acc[2][2];
#pragma unroll
    for (int r = 0; r < 2; ++r)
#pragma unroll
        for (int c = 0; c < 2; ++c) acc[r][c] = (floatx4)0.f;

    const bf16* agb = A + (size_t)(m0 + srow) * 1024 + scg;
    const bf16* bgb = W + (size_t)(n0 + srow) * 1024 + scg;

    bf16x8 av0 = *(const bf16x8*)(const void*)agb;
    bf16x8 av1 = *(const bf16x8*)(const void*)(agb + 8);
    bf16x8 bv0 = *(const bf16x8*)(const void*)bgb;
    bf16x8 bv1 = *(const bf16x8*)(const void*)(bgb + 8);

    for (int k0 = 0; k0 < 1024; k0 += 64) {
        __syncthreads();
        *(bf16x8*)&As[srow][scg]     = av0;
        *(bf16x8*)&As[srow][scg + 8] = av1;
        *(bf16x8*)&Bs[srow][scg]     = bv0;
        *(bf16x8*)&Bs[srow][scg + 8] = bv1;
        __syncthreads();
        if (k0 < 960) {  // prefetch next tile (overlaps MFMA below)
            const bf16* ag = agb + k0 + 64;
            const bf16* bg = bgb + k0 + 64;
            av0 = *(const bf16x8*)(const void*)ag;
            av1 = *(const bf16x8*)(const void*)(ag + 8);
            bv0 = *(const bf16x8*)(const void*)bg;
            bv1 = *(const bf16x8*)(const void*)(bg + 8);
        }
#pragma unroll
        for (int kk = 0; kk < 2; ++kk) {
            bf16x8 af[2], bfr[2];
#pragma unroll
            for (int r = 0; r < 2; ++r)
                af[r] = *(const bf16x8*)&As[wr + r * 16 + l16][kk * 32 + quad * 8];
#pragma unroll
            for (int c = 0; c < 2; ++c)
                bfr[c] = *(const bf16x8*)&Bs[wc + c * 16 + l16][kk * 32 + quad * 8];
#pragma unroll
            for (int r = 0; r < 2; ++r)
#pragma unroll
                for (int c = 0; c < 2; ++c)
                    acc[r][c] = mfma16(af[r], bfr[c], acc[r][c]);
        }
    }
#pragma unroll
    for (int c = 0; c < 2; ++c) {
        const int col = n0 + wc + c * 16 + l16;
        const float bvl = (float)bias[col];
#pragma unroll
        for (int r = 0; r < 2; ++r)
#pragma unroll
            for (int v = 0; v < 4; ++v) {
                const int row = m0 + wr + r * 16 + quad * 4 + v;
                const float val = acc[r][c][v] + bvl;
                const size_t idx = (size_t)row * 1024 + col;
                if (*flag) ((float*)C)[idx] = val;
                else       ((bf16*)C)[idx] = (bf16)val;
            }
    }
}

// ---------------------------------------------------------------------------
extern "C" void kernel_launch(void* const* d_in, const int* in_sizes, int n_in,
                              void* d_out, int out_size, void* d_ws, size_t ws_size,
                              hipStream_t stream) {
    const size_t E_X = 2097152;       // 2048 x 1024
    const size_t E_CANON = 6426624;

    char* ws = (char*)d_ws;
    int* flag = (int*)ws;
    bf16* canon = (bf16*)(ws + 16);
    bf16* xc  = canon;
    bf16* Wqc = canon + 2097152;
    bf16* Wkc = canon + 3145728;
    bf16* Wvc = canon + 4194304;
    bf16* Woc = canon + 5242880;
    bf16* bqc = canon + 6291456;
    bf16* bkc = canon + 6292480;
    bf16* bvc = canon + 6293504;
    bf16* boc = canon + 6294528;
    bf16* Erc = canon + 6295552;
    bf16* p = canon + E_CANON;
    bf16* Qb    = p;  p += E_X;       // reused as Ob after combine
    bf16* Kb    = p;  p += E_X;
    bf16* Vt    = p;  p += E_X;
    bf16* Opart = p;  p += 3 * E_X;   // bf16 unnormalized partials, 3 j-splits
    float* Ml   = (float*)p;          // [3 jsel][2 b][16 h][1024 i] = 98304 f32

    detect_dtype_kernel<<<1, 256, 0, stream>>>(d_in[0], flag);

    ConvSrcs cs;
    cs.p[0] = d_in[0]; cs.p[1] = d_in[1]; cs.p[2] = d_in[3]; cs.p[3] = d_in[5];
    cs.p[4] = d_in[7]; cs.p[5] = d_in[2]; cs.p[6] = d_in[4]; cs.p[7] = d_in[6];
    cs.p[8] = d_in[8]; cs.p[9] = d_in[9];
    convert_all_kernel<<<3138, 256, 0, stream>>>(cs, canon, flag);

    gemm_qkv_kernel<<<dim3(48, 16), 256, 0, stream>>>(xc, Wqc, Wkc, Wvc,
                                                      bqc, bkc, bvc, Qb, Kb, Vt);

    attn_mfma_kernel<<<dim3(8, 16, 6), 256, 0, stream>>>(Qb, Kb, Vt, Erc, Opart, Ml);

    combine_kernel<<<2048, 256, 0, stream>>>(Opart, Ml, Qb);  // Ob overlays Qb

    gemm_out_kernel<<<dim3(16, 32), 256, 0, stream>>>(Qb, Woc, boc, d_out, flag);
}